// Round 4
// baseline (279.716 us; speedup 1.0000x reference)
//
#include <hip/hip_runtime.h>

#define H 65536
#define CIN 64
#define COUT 128
#define NK 27
#define KTOT (NK*CIN)   // 1728
#define NBLK 64         // n-points per block (4 waves: 2 o-halves x 2 n-quarters)

typedef unsigned short u16;
typedef unsigned int   u32;
typedef __attribute__((ext_vector_type(8))) short short8;   // 8 bf16 (MFMA frag)
typedef __attribute__((ext_vector_type(4))) float f32x4;    // MFMA acc
typedef __attribute__((ext_vector_type(4))) unsigned int u32x4;

__device__ __forceinline__ u16 f2bf(float f) {
    u32 u = __float_as_uint(f);
    u = (u + 0x7FFFu + ((u >> 16) & 1u)) >> 16;   // RNE
    return (u16)u;
}

// ---------------------------------------------------------------------------
// Kernel 1a: x (64 x 65536 f32, c-major) -> x_t (65536 x 64 bf16, point-major)
__global__ __launch_bounds__(256) void transpose_x(const float* __restrict__ x,
                                                   u16* __restrict__ xt) {
    const int h = blockIdx.x * 256 + threadIdx.x;
    u32 pk[32];
#pragma unroll
    for (int cp = 0; cp < 32; ++cp) {
        float f0 = x[(2 * cp)     * H + h];
        float f1 = x[(2 * cp + 1) * H + h];
        pk[cp] = (u32)f2bf(f0) | ((u32)f2bf(f1) << 16);
    }
    u32x4* dst = (u32x4*)(xt + (size_t)h * CIN);
#pragma unroll
    for (int i = 0; i < 8; ++i)
        dst[i] = *(u32x4*)&pk[i * 4];
}

// ---------------------------------------------------------------------------
// Kernel 1b: w (128 x 64 x 27 f32) -> wbF, MFMA-fragment-ordered:
// wbF[((fb*27 + k)*2 + hh)*512 + lane*8 + j] = bf16(w[fb*16+(lane&15)][hh*32+(lane>>4)*8+j][k])
// A-fragment load = one fully-coalesced 1KB wave read. Also zeroes BN sums.
__global__ __launch_bounds__(256) void conv_w(const float* __restrict__ w,
                                              u16* __restrict__ wbF,
                                              float* __restrict__ sums) {
    const int tid = blockIdx.x * 256 + threadIdx.x;
    if (blockIdx.x == 0) sums[threadIdx.x] = 0.f;   // sum[128], sumsq[128]
    if (tid < COUT * KTOT) {
        const int jj   = tid & 7;
        const int lane = (tid >> 3) & 63;
        const int hh   = (tid >> 9) & 1;
        const int t2   = tid >> 10;        // fb*27 + k
        const int k    = t2 % 27;
        const int fb   = t2 / 27;
        const int o    = fb * 16 + (lane & 15);
        const int c    = hh * 32 + (lane >> 4) * 8 + jj;
        wbF[tid] = f2bf(w[(o * CIN + c) * NK + k]);
    }
}

// ---------------------------------------------------------------------------
// Kernel 2: fused gather + GEMM + BN partial sums.
// 4 waves/block, each wave = 64o x 32n, fully independent after sIdx staging:
// coalesced row-gather (8 lanes x 16B per 128B row) -> wave-PRIVATE swizzled
// LDS double-buffer -> B fragments. 3-deep register prefetch, NO k-loop
// barriers (same-wave lgkmcnt ordering only). A loaded JIT from wbF (L2-hot).
__global__ __launch_bounds__(256, 3) void conv_mfma(const u16* __restrict__ xt,
                                                    const u16* __restrict__ wbF,
                                                    const int* __restrict__ neigh,
                                                    float* __restrict__ out,
                                                    float* __restrict__ sums) {
    __shared__ __align__(16) u16 sB[4][2][32 * 64];  // 32 KB: per-wave private dbuf
    __shared__ int sIdx[NBLK * NK];                  // 6912 B

    const int tid  = threadIdx.x;
    const int lane = tid & 63;
    const int w    = tid >> 6;        // wave 0..3
    const int wo   = w >> 1;          // o-half (64 each)
    const int wn   = w & 1;           // n-quarter (32 each)
    const int n0   = blockIdx.x * NBLK;

    for (int i = tid; i < NBLK * NK; i += 256)
        sIdx[i] = neigh[n0 * NK + i];
    __syncthreads();                   // only block barrier in the kernel

    const int r16 = lane & 15;
    const int q   = lane >> 4;        // 0..3
    const int pl  = lane >> 3;        // 0..7  (row within group of 8)
    const int cl  = lane & 7;         // 16B chunk within 128B row

    const int* myIdx = sIdx + wn * 32 * NK;
    u16* myB0 = &sB[w][0][0];
    u16* myB1 = &sB[w][1][0];

    f32x4 acc[4][2] = {};              // [o-frag][n-frag]

    const u16* aBase = wbF + (size_t)(wo * 4 * NK) * 1024 + lane * 8;

    u32x4 rgA[4], rgB[4], rgC[4];

#define GATHER(K, RG)                                                    \
    { _Pragma("unroll") for (int it = 0; it < 4; ++it) {                 \
        const int p = it * 8 + pl;                                       \
        const int row = myIdx[p * NK + (K)];                             \
        RG[it] = *(const u32x4*)(xt + (size_t)(u32)row * 64 + cl * 8); } }
#define WRITEB(RG, BUF)                                                  \
    { _Pragma("unroll") for (int it = 0; it < 4; ++it) {                 \
        const int p = it * 8 + pl;                                       \
        *(u32x4*)((BUF) + p * 64 + (cl ^ (p & 7)) * 8) = RG[it]; } }

#define BODY(J, WRG, GRG)                                                \
    {                                                                    \
        u16* bufc = ((J) & 1) ? myB1 : myB0;                             \
        u16* bufn = ((J) & 1) ? myB0 : myB1;                             \
        if ((J) + 1 < NK) WRITEB(WRG, bufn)                              \
        if ((J) + 3 < NK) GATHER((J) + 3, GRG)                           \
        short8 af[4][2];                                                 \
        _Pragma("unroll") for (int f = 0; f < 4; ++f) {                  \
            const u16* p = aBase + (size_t)(f * NK + (J)) * 1024;        \
            af[f][0] = *(const short8*)(p);                              \
            af[f][1] = *(const short8*)(p + 512); }                      \
        short8 bf[2][2];                                                 \
        _Pragma("unroll") for (int nf = 0; nf < 2; ++nf)                 \
        _Pragma("unroll") for (int hh = 0; hh < 2; ++hh) {               \
            const int p = nf * 16 + r16;                                 \
            const int slin = q + hh * 4;                                 \
            bf[nf][hh] = *(const short8*)(bufc + p * 64 +                \
                                          (slin ^ (p & 7)) * 8); }       \
        _Pragma("unroll") for (int hh = 0; hh < 2; ++hh)                 \
        _Pragma("unroll") for (int f = 0; f < 4; ++f)                    \
        _Pragma("unroll") for (int nf = 0; nf < 2; ++nf)                 \
            acc[f][nf] = __builtin_amdgcn_mfma_f32_16x16x32_bf16(        \
                af[f][hh], bf[nf][hh], acc[f][nf], 0, 0, 0);             \
    }

    // prologue: k0 staged to LDS; k1,k2 in flight in regs
    GATHER(0, rgA)
    WRITEB(rgA, myB0)
    GATHER(1, rgB)
    GATHER(2, rgC)

    for (int j = 0; j < NK; j += 3) {          // 27 = 9 triplets
        BODY(j,     rgB, rgA)
        BODY(j + 1, rgC, rgB)
        BODY(j + 2, rgA, rgC)
    }
#undef GATHER
#undef WRITEB
#undef BODY

    // epilogue: C/D layout: col(n) = lane&15, row(o) = q*4 + r
#pragma unroll
    for (int f = 0; f < 4; ++f)
#pragma unroll
        for (int nf = 0; nf < 2; ++nf)
#pragma unroll
            for (int r = 0; r < 4; ++r) {
                const int o = wo * 64 + f * 16 + q * 4 + r;
                const int n = n0 + wn * 32 + nf * 16 + r16;
                out[(size_t)o * H + n] = acc[f][nf][r];
            }

    // fused BN partial sums: reduce this wave's 32 n per o, one atomic per o
#pragma unroll
    for (int f = 0; f < 4; ++f)
#pragma unroll
        for (int r = 0; r < 4; ++r) {
            float sv = acc[f][0][r] + acc[f][1][r];
            float sq = acc[f][0][r] * acc[f][0][r] + acc[f][1][r] * acc[f][1][r];
#pragma unroll
            for (int m = 1; m < 16; m <<= 1) {
                sv += __shfl_xor(sv, m, 64);
                sq += __shfl_xor(sq, m, 64);
            }
            if (r16 == 0) {
                const int o = wo * 64 + f * 16 + q * 4 + r;
                atomicAdd(&sums[o], sv);
                atomicAdd(&sums[COUT + o], sq);
            }
        }
}

// ---------------------------------------------------------------------------
// Kernel 3: BN + ReLU with inline stats (sums accumulated by conv), float4.
__global__ __launch_bounds__(256) void bn_relu(float* __restrict__ out,
                                               const float* __restrict__ sums,
                                               const float* __restrict__ gamma,
                                               const float* __restrict__ beta) {
    const int idx = blockIdx.x * 256 + threadIdx.x;  // float4 index
    const int o = idx >> 14;                          // 16384 float4 per channel
    const float mean = sums[o] * (1.f / (float)H);
    const float var  = sums[COUT + o] * (1.f / (float)H) - mean * mean;
    const float a = gamma[o] * rsqrtf(var + 1e-5f);
    const float b = beta[o] - mean * a;
    float4* p = (float4*)out;
    float4 v = p[idx];
    v.x = fmaxf(fmaf(v.x, a, b), 0.f);
    v.y = fmaxf(fmaf(v.y, a, b), 0.f);
    v.z = fmaxf(fmaf(v.z, a, b), 0.f);
    v.w = fmaxf(fmaf(v.w, a, b), 0.f);
    p[idx] = v;
}

// ---------------------------------------------------------------------------
extern "C" void kernel_launch(void* const* d_in, const int* in_sizes, int n_in,
                              void* d_out, int out_size, void* d_ws, size_t ws_size,
                              hipStream_t stream) {
    const float* x     = (const float*)d_in[0];  // (1,64,65536,1)
    const int*   neigh = (const int*)d_in[1];    // (65536,27)
    const float* w     = (const float*)d_in[2];  // (128,64,27)
    const float* gamma = (const float*)d_in[3];
    const float* beta  = (const float*)d_in[4];
    float* out = (float*)d_out;                  // (1,128,65536,1)

    char* ws = (char*)d_ws;
    u16* xt  = (u16*)ws;                              // 8388608 B
    u16* wbF = (u16*)(ws + 8388608);                  // 442368 B
    float* sums = (float*)(ws + 8388608 + 442368);    // 256 floats

    transpose_x<<<H / 256, 256, 0, stream>>>(x, xt);
    conv_w<<<(COUT * KTOT + 255) / 256, 256, 0, stream>>>(w, wbF, sums);
    conv_mfma<<<H / NBLK, 256, 0, stream>>>(xt, wbF, neigh, out, sums);
    bn_relu<<<(COUT * H / 4) / 256, 256, 0, stream>>>(out, sums, gamma, beta);
}

// Round 5
// 154.155 us; speedup vs baseline: 1.8145x; 1.8145x over previous
//
#include <hip/hip_runtime.h>

#define H 65536
#define CIN 64
#define COUT 128
#define NK 27
#define KTOT (NK*CIN)   // 1728
#define NBLK 64         // points per block; 4 waves, each 32o x 64n

typedef unsigned short u16;
typedef unsigned int   u32;
typedef __attribute__((ext_vector_type(8))) short short8;   // 8 bf16 (MFMA frag)
typedef __attribute__((ext_vector_type(4))) float f32x4;    // MFMA acc
typedef __attribute__((ext_vector_type(4))) unsigned int u32x4;

__device__ __forceinline__ u16 f2bf(float f) {
    u32 u = __float_as_uint(f);
    u = (u + 0x7FFFu + ((u >> 16) & 1u)) >> 16;   // RNE
    return (u16)u;
}

// ---------------------------------------------------------------------------
// Kernel 1a: x (64 x 65536 f32, c-major) -> x_t (65536 x 64 bf16, point-major)
__global__ __launch_bounds__(256) void transpose_x(const float* __restrict__ x,
                                                   u16* __restrict__ xt) {
    const int h = blockIdx.x * 256 + threadIdx.x;
    u32 pk[32];
#pragma unroll
    for (int cp = 0; cp < 32; ++cp) {
        float f0 = x[(2 * cp)     * H + h];
        float f1 = x[(2 * cp + 1) * H + h];
        pk[cp] = (u32)f2bf(f0) | ((u32)f2bf(f1) << 16);
    }
    u32x4* dst = (u32x4*)(xt + (size_t)h * CIN);
#pragma unroll
    for (int i = 0; i < 8; ++i)
        dst[i] = *(u32x4*)&pk[i * 4];
}

// ---------------------------------------------------------------------------
// Kernel 1b: w (128 x 64 x 27 f32) -> wbF, MFMA-fragment-ordered:
// wbF[((fb*27 + k)*2 + hh)*512 + lane*8 + j] = bf16(w[fb*16+(lane&15)][hh*32+(lane>>4)*8+j][k])
// A-fragment load = one fully-coalesced 1KB wave read. Also zeroes BN sums.
__global__ __launch_bounds__(256) void conv_w(const float* __restrict__ w,
                                              u16* __restrict__ wbF,
                                              float* __restrict__ sums) {
    const int tid = blockIdx.x * 256 + threadIdx.x;
    if (blockIdx.x == 0) sums[threadIdx.x] = 0.f;   // sum[128], sumsq[128]
    if (tid < COUT * KTOT) {
        const int jj   = tid & 7;
        const int lane = (tid >> 3) & 63;
        const int hh   = (tid >> 9) & 1;
        const int t2   = tid >> 10;        // fb*27 + k
        const int k    = t2 % 27;
        const int fb   = t2 / 27;
        const int o    = fb * 16 + (lane & 15);
        const int c    = hh * 32 + (lane >> 4) * 8 + jj;
        wbF[tid] = f2bf(w[(o * CIN + c) * NK + k]);
    }
}

// ---------------------------------------------------------------------------
// Kernel 2: fused gather + GEMM + BN partial sums.
// 4-deep global_load_lds pipeline, counted vmcnt(6), raw s_barrier (1/k-step).
// Tile 128o x 64n, 4 waves each 32o x 64n. Gather pre-swizzled at the global
// source (chunk cl^pl) so the linear LDS dest gets the XOR-swizzled layout.
__global__ __launch_bounds__(256, 4) void conv_mfma(const u16* __restrict__ xt,
                                                    const u16* __restrict__ wbF,
                                                    const int* __restrict__ neigh,
                                                    float* __restrict__ out,
                                                    float* __restrict__ sums) {
    __shared__ __align__(16) u16 sB[4][NBLK * CIN];  // 4 x 8 KB ring
    __shared__ int sIdx[NBLK * NK];                  // 6912 B

    const int tid  = threadIdx.x;
    const int lane = tid & 63;
    const int w    = tid >> 6;        // wave 0..3 -> o-range w*32..+31
    const int n0   = blockIdx.x * NBLK;

    for (int i = tid; i < NBLK * NK; i += 256)
        sIdx[i] = neigh[n0 * NK + i];
    __syncthreads();

    const int r16 = lane & 15;
    const int q   = lane >> 4;        // 0..3
    const int pl  = lane >> 3;        // row-within-8
    const int cl  = lane & 7;         // 16B chunk
    const int swz = (cl ^ pl) * 8;    // pre-swizzled source chunk (u16 units)

    f32x4 acc[2][4] = {};             // [o-frag][n-frag]
    const u16* aBase = wbF + (size_t)(w * 2 * NK) * 1024 + lane * 8;

    // one global_load_lds: 64 lanes x 16B, rows w*16+it*8 .. +7, linear LDS dest
#define GLL(K, IT)                                                            \
    {                                                                         \
        const int p_   = w * 16 + (IT) * 8 + pl;                              \
        const int row_ = sIdx[p_ * NK + (K)];                                 \
        const u16* g_  = xt + (size_t)(u32)row_ * 64 + swz;                   \
        u16* l_ = &sB[(K) & 3][(w * 16 + (IT) * 8) * 64];                     \
        __builtin_amdgcn_global_load_lds(                                     \
            (const __attribute__((address_space(1))) void*)g_,                \
            (__attribute__((address_space(3))) void*)l_, 16, 0, 0);           \
    }
#define GSTEP(K) { GLL(K, 0) GLL(K, 1) }

#define A_LOAD(K, AF)                                                         \
    { _Pragma("unroll") for (int f = 0; f < 2; ++f)                           \
      _Pragma("unroll") for (int hh = 0; hh < 2; ++hh)                        \
        AF[f][hh] = *(const short8*)(aBase +                                  \
            (size_t)(f * NK + (K)) * 1024 + hh * 512); }

#define MFMA_STEP(K, AF)                                                      \
    { _Pragma("unroll") for (int hh = 0; hh < 2; ++hh) {                      \
        short8 bfr[4];                                                        \
        _Pragma("unroll") for (int nf = 0; nf < 4; ++nf) {                    \
            const int p_ = nf * 16 + r16;                                     \
            const int sl_ = (hh * 4 + q) ^ (r16 & 7);                         \
            bfr[nf] = *(const short8*)(&sB[(K) & 3][p_ * 64 + sl_ * 8]);      \
        }                                                                     \
        _Pragma("unroll") for (int f = 0; f < 2; ++f)                         \
        _Pragma("unroll") for (int nf = 0; nf < 4; ++nf)                      \
            acc[f][nf] = __builtin_amdgcn_mfma_f32_16x16x32_bf16(             \
                AF[f][hh], bfr[nf], acc[f][nf], 0, 0, 0);                     \
    } }

// STEP: counted-vmcnt wait (staging k + A(k) done; newest stays in flight),
// barrier, then issue next A and next staging BEFORE the MFMA cluster.
#define STEP(K, CUR, NXT)                                                     \
    {                                                                         \
        asm volatile("s_waitcnt vmcnt(6)" ::: "memory");                      \
        __builtin_amdgcn_s_barrier();                                         \
        A_LOAD((K) + 1, NXT)                                                  \
        if ((K) + 3 < NK) GSTEP((K) + 3)                                      \
        MFMA_STEP(K, CUR)                                                     \
    }

    short8 afA[2][2], afB[2][2];

    // prologue: buffer 0,1,2 staged; A(0) issued between G(0) and G(1)
    GSTEP(0)
    A_LOAD(0, afA)
    GSTEP(1)
    GSTEP(2)

    for (int k = 0; k < NK - 1; k += 2) {   // 13 pairs: k = 0..25
        STEP(k,     afA, afB)
        STEP(k + 1, afB, afA)
    }
    // k = 26
    asm volatile("s_waitcnt vmcnt(0)" ::: "memory");
    __builtin_amdgcn_s_barrier();
    MFMA_STEP(26, afA)

#undef GLL
#undef GSTEP
#undef A_LOAD
#undef MFMA_STEP
#undef STEP

    // epilogue: C/D layout: col(n) = lane&15, row(o) = q*4 + r
#pragma unroll
    for (int f = 0; f < 2; ++f)
#pragma unroll
        for (int nf = 0; nf < 4; ++nf)
#pragma unroll
            for (int r = 0; r < 4; ++r) {
                const int o = w * 32 + f * 16 + q * 4 + r;
                const int n = n0 + nf * 16 + r16;
                out[(size_t)o * H + n] = acc[f][nf][r];
            }

    // fused BN partial sums: reduce this wave's 64 n per o, one atomic per o
#pragma unroll
    for (int f = 0; f < 2; ++f)
#pragma unroll
        for (int r = 0; r < 4; ++r) {
            float sv = acc[f][0][r] + acc[f][1][r] + acc[f][2][r] + acc[f][3][r];
            float sq = acc[f][0][r] * acc[f][0][r] + acc[f][1][r] * acc[f][1][r]
                     + acc[f][2][r] * acc[f][2][r] + acc[f][3][r] * acc[f][3][r];
#pragma unroll
            for (int m = 1; m < 16; m <<= 1) {
                sv += __shfl_xor(sv, m, 64);
                sq += __shfl_xor(sq, m, 64);
            }
            if (r16 == 0) {
                const int o = w * 32 + f * 16 + q * 4 + r;
                atomicAdd(&sums[o], sv);
                atomicAdd(&sums[COUT + o], sq);
            }
        }
}

// ---------------------------------------------------------------------------
// Kernel 3: BN + ReLU with inline stats (sums accumulated by conv), float4.
__global__ __launch_bounds__(256) void bn_relu(float* __restrict__ out,
                                               const float* __restrict__ sums,
                                               const float* __restrict__ gamma,
                                               const float* __restrict__ beta) {
    const int idx = blockIdx.x * 256 + threadIdx.x;  // float4 index
    const int o = idx >> 14;                          // 16384 float4 per channel
    const float mean = sums[o] * (1.f / (float)H);
    const float var  = sums[COUT + o] * (1.f / (float)H) - mean * mean;
    const float a = gamma[o] * rsqrtf(var + 1e-5f);
    const float b = beta[o] - mean * a;
    float4* p = (float4*)out;
    float4 v = p[idx];
    v.x = fmaxf(fmaf(v.x, a, b), 0.f);
    v.y = fmaxf(fmaf(v.y, a, b), 0.f);
    v.z = fmaxf(fmaf(v.z, a, b), 0.f);
    v.w = fmaxf(fmaf(v.w, a, b), 0.f);
    p[idx] = v;
}

// ---------------------------------------------------------------------------
extern "C" void kernel_launch(void* const* d_in, const int* in_sizes, int n_in,
                              void* d_out, int out_size, void* d_ws, size_t ws_size,
                              hipStream_t stream) {
    const float* x     = (const float*)d_in[0];  // (1,64,65536,1)
    const int*   neigh = (const int*)d_in[1];    // (65536,27)
    const float* w     = (const float*)d_in[2];  // (128,64,27)
    const float* gamma = (const float*)d_in[3];
    const float* beta  = (const float*)d_in[4];
    float* out = (float*)d_out;                  // (1,128,65536,1)

    char* ws = (char*)d_ws;
    u16* xt  = (u16*)ws;                              // 8388608 B
    u16* wbF = (u16*)(ws + 8388608);                  // 442368 B
    float* sums = (float*)(ws + 8388608 + 442368);    // 256 floats

    transpose_x<<<H / 256, 256, 0, stream>>>(x, xt);
    conv_w<<<(COUT * KTOT + 255) / 256, 256, 0, stream>>>(w, wbF, sums);
    conv_mfma<<<H / NBLK, 256, 0, stream>>>(xt, wbF, neigh, out, sums);
    bn_relu<<<(COUT * H / 4) / 256, 256, 0, stream>>>(out, sums, gamma, beta);
}

// Round 6
// 147.758 us; speedup vs baseline: 1.8931x; 1.0433x over previous
//
#include <hip/hip_runtime.h>

#define H 65536
#define CIN 64
#define COUT 128
#define NK 27
#define KTOT (NK*CIN)   // 1728
#define NBLK 64         // points per block; 4 waves, each 32o x 64n

typedef unsigned short u16;
typedef unsigned int   u32;
typedef __attribute__((ext_vector_type(8))) short short8;   // 8 bf16 (MFMA frag)
typedef __attribute__((ext_vector_type(4))) float f32x4;    // MFMA acc
typedef __attribute__((ext_vector_type(4))) unsigned int u32x4;

__device__ __forceinline__ u16 f2bf(float f) {
    u32 u = __float_as_uint(f);
    u = (u + 0x7FFFu + ((u >> 16) & 1u)) >> 16;   // RNE
    return (u16)u;
}

// ---------------------------------------------------------------------------
// Kernel 1a: x (64 x 65536 f32, c-major) -> x_t (65536 x 64 bf16, point-major)
__global__ __launch_bounds__(256) void transpose_x(const float* __restrict__ x,
                                                   u16* __restrict__ xt) {
    const int h = blockIdx.x * 256 + threadIdx.x;
    u32 pk[32];
#pragma unroll
    for (int cp = 0; cp < 32; ++cp) {
        float f0 = x[(2 * cp)     * H + h];
        float f1 = x[(2 * cp + 1) * H + h];
        pk[cp] = (u32)f2bf(f0) | ((u32)f2bf(f1) << 16);
    }
    u32x4* dst = (u32x4*)(xt + (size_t)h * CIN);
#pragma unroll
    for (int i = 0; i < 8; ++i)
        dst[i] = *(u32x4*)&pk[i * 4];
}

// ---------------------------------------------------------------------------
// Kernel 1b: w (128 x 64 x 27 f32) -> wbF, MFMA-fragment-ordered:
// wbF[((fb*27 + k)*2 + hh)*512 + lane*8 + j] = bf16(w[fb*16+(lane&15)][hh*32+(lane>>4)*8+j][k])
// A-fragment load = one fully-coalesced 1KB wave read. Also zeroes BN sums.
__global__ __launch_bounds__(256) void conv_w(const float* __restrict__ w,
                                              u16* __restrict__ wbF,
                                              float* __restrict__ sums) {
    const int tid = blockIdx.x * 256 + threadIdx.x;
    if (blockIdx.x == 0) sums[threadIdx.x] = 0.f;   // sum[128], sumsq[128]
    if (tid < COUT * KTOT) {
        const int jj   = tid & 7;
        const int lane = (tid >> 3) & 63;
        const int hh   = (tid >> 9) & 1;
        const int t2   = tid >> 10;        // fb*27 + k
        const int k    = t2 % 27;
        const int fb   = t2 / 27;
        const int o    = fb * 16 + (lane & 15);
        const int c    = hh * 32 + (lane >> 4) * 8 + jj;
        wbF[tid] = f2bf(w[(o * CIN + c) * NK + k]);
    }
}

// ---------------------------------------------------------------------------
// Kernel 2: fused gather + GEMM + BN partial sums.
// R1's proven 2-barrier LDS double-buffer, but with 3-step issue distance:
// at step k: write gather(k+1) (issued at k-2 -> ~2 phases of latency cover),
// issue gather(k+3). 3-set register rotation, fully unrolled so all rotation
// indices are compile-time. A from fragment-ordered wbF (coalesced, 1-deep).
__global__ __launch_bounds__(256, 4) void conv_mfma(const u16* __restrict__ xt,
                                                    const u16* __restrict__ wbF,
                                                    const int* __restrict__ neigh,
                                                    float* __restrict__ out,
                                                    float* __restrict__ sums) {
    __shared__ __align__(16) u16 sB[2][NBLK * CIN];  // 2 x 8 KB
    __shared__ int sIdx[NBLK * NK];                  // 6912 B

    const int tid  = threadIdx.x;
    const int lane = tid & 63;
    const int w    = tid >> 6;        // wave 0..3 -> o-range w*32..+31
    const int n0   = blockIdx.x * NBLK;

    for (int i = tid; i < NBLK * NK; i += 256)
        sIdx[i] = neigh[n0 * NK + i];
    __syncthreads();

    const int r16 = lane & 15;
    const int q   = lane >> 4;        // 0..3
    const int pl  = lane >> 3;        // 0..7 row-within-8
    const int cl  = lane & 7;         // 16B chunk within 128B row

    f32x4 acc[2][4] = {};             // [o-frag][n-frag]
    const u16* aBase = wbF + (size_t)(w * 2 * NK) * 1024 + lane * 8;

    u32x4 rg[3][2];                   // 3-deep gather rotation
    short8 af[2][2][2];               // A double buffer [k&1][f][hh]

#define GATHER(K, RG)                                                        \
    { _Pragma("unroll") for (int it = 0; it < 2; ++it) {                     \
        const int p_ = w * 16 + it * 8 + pl;                                 \
        const int row_ = sIdx[p_ * NK + (K)];                                \
        RG[it] = *(const u32x4*)(xt + (size_t)(u32)row_ * 64 + cl * 8); } }
#define WRITEB(RG, BUF)                                                      \
    { _Pragma("unroll") for (int it = 0; it < 2; ++it) {                     \
        const int p_ = w * 16 + it * 8 + pl;                                 \
        *(u32x4*)((BUF) + p_ * 64 + ((cl ^ (p_ & 7)) * 8)) = RG[it]; } }
#define A_LOAD(K, AF)                                                        \
    { _Pragma("unroll") for (int f = 0; f < 2; ++f)                          \
      _Pragma("unroll") for (int hh = 0; hh < 2; ++hh)                       \
        AF[f][hh] = *(const short8*)(aBase +                                 \
            (size_t)(f * NK + (K)) * 1024 + hh * 512); }

    // prologue: 3 gathers in flight, A(0) loaded, buf0 staged
    GATHER(0, rg[0])
    GATHER(1, rg[1])
    A_LOAD(0, af[0])
    GATHER(2, rg[2])
    WRITEB(rg[0], &sB[0][0])

#pragma unroll
    for (int k = 0; k < NK; ++k) {    // fully unrolled: %3 / &1 fold to consts
        __syncthreads();              // all waves done reading buf[(k+1)&1]
        if (k + 1 < NK) WRITEB(rg[(k + 1) % 3], &sB[(k + 1) & 1][0])
        if (k + 3 < NK) GATHER(k + 3, rg[k % 3])
        if (k + 1 < NK) A_LOAD(k + 1, af[(k + 1) & 1])
        __syncthreads();              // buf[k&1] complete (written at step k-1)
#pragma unroll
        for (int hh = 0; hh < 2; ++hh) {
            short8 bfr[4];
#pragma unroll
            for (int nf = 0; nf < 4; ++nf) {
                const int p_ = nf * 16 + r16;
                const int sl_ = (hh * 4 + q) ^ (p_ & 7);
                bfr[nf] = *(const short8*)(&sB[k & 1][p_ * 64 + sl_ * 8]);
            }
#pragma unroll
            for (int f = 0; f < 2; ++f)
#pragma unroll
                for (int nf = 0; nf < 4; ++nf)
                    acc[f][nf] = __builtin_amdgcn_mfma_f32_16x16x32_bf16(
                        af[k & 1][f][hh], bfr[nf], acc[f][nf], 0, 0, 0);
        }
    }

#undef GATHER
#undef WRITEB
#undef A_LOAD

    // epilogue: C/D layout: col(n) = lane&15, row(o) = q*4 + r
#pragma unroll
    for (int f = 0; f < 2; ++f)
#pragma unroll
        for (int nf = 0; nf < 4; ++nf)
#pragma unroll
            for (int r = 0; r < 4; ++r) {
                const int o = w * 32 + f * 16 + q * 4 + r;
                const int n = n0 + nf * 16 + r16;
                out[(size_t)o * H + n] = acc[f][nf][r];
            }

    // fused BN partial sums: reduce this wave's 64 n per o, one atomic per o
#pragma unroll
    for (int f = 0; f < 2; ++f)
#pragma unroll
        for (int r = 0; r < 4; ++r) {
            float sv = acc[f][0][r] + acc[f][1][r] + acc[f][2][r] + acc[f][3][r];
            float sq = acc[f][0][r] * acc[f][0][r] + acc[f][1][r] * acc[f][1][r]
                     + acc[f][2][r] * acc[f][2][r] + acc[f][3][r] * acc[f][3][r];
#pragma unroll
            for (int m = 1; m < 16; m <<= 1) {
                sv += __shfl_xor(sv, m, 64);
                sq += __shfl_xor(sq, m, 64);
            }
            if (r16 == 0) {
                const int o = w * 32 + f * 16 + q * 4 + r;
                atomicAdd(&sums[o], sv);
                atomicAdd(&sums[COUT + o], sq);
            }
        }
}

// ---------------------------------------------------------------------------
// Kernel 3: BN + ReLU with inline stats (sums accumulated by conv), float4.
__global__ __launch_bounds__(256) void bn_relu(float* __restrict__ out,
                                               const float* __restrict__ sums,
                                               const float* __restrict__ gamma,
                                               const float* __restrict__ beta) {
    const int idx = blockIdx.x * 256 + threadIdx.x;  // float4 index
    const int o = idx >> 14;                          // 16384 float4 per channel
    const float mean = sums[o] * (1.f / (float)H);
    const float var  = sums[COUT + o] * (1.f / (float)H) - mean * mean;
    const float a = gamma[o] * rsqrtf(var + 1e-5f);
    const float b = beta[o] - mean * a;
    float4* p = (float4*)out;
    float4 v = p[idx];
    v.x = fmaxf(fmaf(v.x, a, b), 0.f);
    v.y = fmaxf(fmaf(v.y, a, b), 0.f);
    v.z = fmaxf(fmaf(v.z, a, b), 0.f);
    v.w = fmaxf(fmaf(v.w, a, b), 0.f);
    p[idx] = v;
}

// ---------------------------------------------------------------------------
extern "C" void kernel_launch(void* const* d_in, const int* in_sizes, int n_in,
                              void* d_out, int out_size, void* d_ws, size_t ws_size,
                              hipStream_t stream) {
    const float* x     = (const float*)d_in[0];  // (1,64,65536,1)
    const int*   neigh = (const int*)d_in[1];    // (65536,27)
    const float* w     = (const float*)d_in[2];  // (128,64,27)
    const float* gamma = (const float*)d_in[3];
    const float* beta  = (const float*)d_in[4];
    float* out = (float*)d_out;                  // (1,128,65536,1)

    char* ws = (char*)d_ws;
    u16* xt  = (u16*)ws;                              // 8388608 B
    u16* wbF = (u16*)(ws + 8388608);                  // 442368 B
    float* sums = (float*)(ws + 8388608 + 442368);    // 256 floats

    transpose_x<<<H / 256, 256, 0, stream>>>(x, xt);
    conv_w<<<(COUT * KTOT + 255) / 256, 256, 0, stream>>>(w, wbF, sums);
    conv_mfma<<<H / NBLK, 256, 0, stream>>>(xt, wbF, neigh, out, sums);
    bn_relu<<<(COUT * H / 4) / 256, 256, 0, stream>>>(out, sums, gamma, beta);
}